// Round 1
// baseline (39.384 us; speedup 1.0000x reference)
//
#include <hip/hip_runtime.h>
#include <hip/hip_bf16.h>

typedef float  f32x4  __attribute__((ext_vector_type(4)));
typedef __bf16 bf16x8 __attribute__((ext_vector_type(8)));
typedef unsigned int u32x4 __attribute__((ext_vector_type(4)));

#define NB 32
#define NA 64
#define NF 128
#define NC 128

// ---------------------------------------------------------------------------
// prep: u[b,a,c] = x[b,a,:] @ W0[0:128, c]
//       v[b,a,c] = x[b,a,:] @ W0[128:256, c] + b0[c]
//       w1t[n,k] = bf16(W1[k,n])   (transposed so B-frags are contiguous in K)
// ---------------------------------------------------------------------------
__global__ __launch_bounds__(128) void prep_kernel(
    const float* __restrict__ x, const float* __restrict__ W0,
    const float* __restrict__ b0, const float* __restrict__ W1,
    float* __restrict__ u, float* __restrict__ v,
    unsigned short* __restrict__ w1t)
{
    int blk = blockIdx.x;
    int tid = threadIdx.x;
    if (blk < 256) {
        // 8 atoms per block: b in [0,32), group g in [0,8)
        __shared__ __align__(16) float xs[8 * 128];
        int b = blk >> 3;
        int g = blk & 7;
        const f32x4* xg = (const f32x4*)(x + (size_t)(b * NA + g * 8) * NF);
        ((f32x4*)xs)[tid]       = xg[tid];
        ((f32x4*)xs)[tid + 128] = xg[tid + 128];
        __syncthreads();
        float uacc[8], vacc[8];
        #pragma unroll
        for (int a = 0; a < 8; ++a) { uacc[a] = 0.f; vacc[a] = 0.f; }
        int c = tid;
        for (int f = 0; f < 128; ++f) {
            float wa = W0[f * NC + c];
            float wb = W0[(NF + f) * NC + c];
            #pragma unroll
            for (int a = 0; a < 8; ++a) {
                uacc[a] = fmaf(xs[a * 128 + f], wa, uacc[a]);
                vacc[a] = fmaf(xs[a * 128 + f], wb, vacc[a]);
            }
        }
        float bias = b0[c];
        #pragma unroll
        for (int a = 0; a < 8; ++a) {
            int row = b * NA + g * 8 + a;
            u[(size_t)row * NC + c] = uacc[a];
            v[(size_t)row * NC + c] = vacc[a] + bias;
        }
    } else {
        // W1 transpose + bf16 cast: 16384 elements, 32 blocks x 128 thr x 4
        int idx = (blk - 256) * 512 + tid * 4;
        int n = idx >> 7;
        int k = idx & 127;
        #pragma unroll
        for (int e = 0; e < 4; ++e) {
            float w = W1[(size_t)(k + e) * NC + n];
            w1t[(size_t)n * NC + k + e] =
                __builtin_bit_cast(unsigned short, (__bf16)w);
        }
    }
}

// ---------------------------------------------------------------------------
// main: per (batch, unordered tile pair (I,J)), compute
//   G1[r=(i,j)] = relu( relu(u_I[i]+v_J[j]) @ W1 + b1 )
//   G2[r=(i,j)] = relu( relu(u_J[j]+v_I[i]) @ W1 + b1 )
//   out(i,j) = out(j,i) = G1[r] + G2[r]
// 512 threads = 8 waves; wave w owns pair-rows r in [32w, 32w+32) of the
// 256-row tile (i_local = 2w+m fixed per 16-row M-frag, j_local = 0..15).
// ---------------------------------------------------------------------------
__device__ inline bf16x8 relu_cvt_bf16(f32x4 a, f32x4 b)
{
    bf16x8 r;
    #pragma unroll
    for (int e = 0; e < 4; ++e) {
        r[e]     = (__bf16)fmaxf(a[e], 0.f);
        r[e + 4] = (__bf16)fmaxf(b[e], 0.f);
    }
    return r;
}

__global__ __launch_bounds__(512, 2) void pair_mlp_kernel(
    const float* __restrict__ b1g, const float* __restrict__ u,
    const float* __restrict__ v, const unsigned short* __restrict__ w1t,
    float* __restrict__ out)
{
    // 64 KB LDS total
    __shared__ __align__(16) float          u_s[2][16 * 128]; // [I/J][row][k]
    __shared__ __align__(16) float          v_s[2][16 * 128];
    __shared__ __align__(16) unsigned short w_s[128 * 128];   // W1^T [n][k]

    int blk = blockIdx.x;
    int b = blk / 10;
    int t = blk % 10;
    int I, J;
    if      (t < 4) { I = 0; J = t;     }
    else if (t < 7) { I = 1; J = t - 3; }
    else if (t < 9) { I = 2; J = t - 5; }
    else            { I = 3; J = 3;     }

    int tid = threadIdx.x;

    // ---- stage u/v tiles, 16B-chunk XOR swizzle (kills stride-512B conflicts)
    {
        int row = tid >> 5;   // 0..15
        int c   = tid & 31;   // 16B chunk within the 128-float row
        int sc  = (c & 16) | ((c ^ row) & 15);
        const f32x4* ugI = (const f32x4*)(u + (size_t)(b * NA + I * 16 + row) * NC);
        const f32x4* ugJ = (const f32x4*)(u + (size_t)(b * NA + J * 16 + row) * NC);
        const f32x4* vgI = (const f32x4*)(v + (size_t)(b * NA + I * 16 + row) * NC);
        const f32x4* vgJ = (const f32x4*)(v + (size_t)(b * NA + J * 16 + row) * NC);
        ((f32x4*)&u_s[0][row * 128])[sc] = ugI[c];
        ((f32x4*)&u_s[1][row * 128])[sc] = ugJ[c];
        ((f32x4*)&v_s[0][row * 128])[sc] = vgI[c];
        ((f32x4*)&v_s[1][row * 128])[sc] = vgJ[c];
    }
    // ---- stage W1^T bf16, chunk swizzle
    #pragma unroll
    for (int p = 0; p < 4; ++p) {
        int chunk = tid + p * 512;   // 0..2047 (16B chunks)
        int n = chunk >> 4;          // 128 rows, 16 chunks/row
        int c = chunk & 15;
        int sc = c ^ (n & 15);
        ((u32x4*)&w_s[n * 128])[sc] = ((const u32x4*)(w1t + (size_t)n * 128))[c];
    }
    __syncthreads();

    int wave = tid >> 6;
    int lane = tid & 63;
    int lhi  = lane >> 4;   // 0..3
    int llo  = lane & 15;   // 0..15

    float bias[8];
    #pragma unroll
    for (int nf = 0; nf < 8; ++nf) bias[nf] = b1g[nf * 16 + llo];

    f32x4 acc1[2][8], acc2[2][8];
    f32x4 z = {0.f, 0.f, 0.f, 0.f};
    #pragma unroll
    for (int m = 0; m < 2; ++m)
        #pragma unroll
        for (int nf = 0; nf < 8; ++nf) { acc1[m][nf] = z; acc2[m][nf] = z; }

    #pragma unroll
    for (int kk = 0; kk < 4; ++kk) {
        int kbase = kk * 32 + lhi * 8;   // this lane-group's K offset
        int kc = kbase >> 2;             // fp32 16B-chunk index (even)
        int wc = kbase >> 3;             // bf16 16B-chunk index

        // B fragments: W1^T[n][kbase..kbase+7]
        bf16x8 bfr[8];
        #pragma unroll
        for (int nf = 0; nf < 8; ++nf) {
            int n = nf * 16 + llo;
            int sc = wc ^ (n & 15);
            bfr[nf] = ((const bf16x8*)&w_s[n * 128])[sc];
        }

        // per-lane row (llo) reads — shared across both M-frags, hoist
        int scv0 = (kc & 16) | ((kc ^ llo) & 15);
        int scv1 = ((kc + 1) & 16) | (((kc + 1) ^ llo) & 15);
        f32x4 vJa = ((const f32x4*)&v_s[1][llo * 128])[scv0];
        f32x4 vJb = ((const f32x4*)&v_s[1][llo * 128])[scv1];
        f32x4 uJa = ((const f32x4*)&u_s[1][llo * 128])[scv0];
        f32x4 uJb = ((const f32x4*)&u_s[1][llo * 128])[scv1];

        bf16x8 a1f[2], a2f[2];
        #pragma unroll
        for (int m = 0; m < 2; ++m) {
            int iu = wave * 2 + m;       // i_local, wave-uniform
            int scu0 = (kc & 16) | ((kc ^ iu) & 15);
            int scu1 = ((kc + 1) & 16) | (((kc + 1) ^ iu) & 15);
            f32x4 uIa = ((const f32x4*)&u_s[0][iu * 128])[scu0];
            f32x4 uIb = ((const f32x4*)&u_s[0][iu * 128])[scu1];
            f32x4 vIa = ((const f32x4*)&v_s[0][iu * 128])[scu0];
            f32x4 vIb = ((const f32x4*)&v_s[0][iu * 128])[scu1];
            a1f[m] = relu_cvt_bf16(uIa + vJa, uIb + vJb); // h(i,j)
            a2f[m] = relu_cvt_bf16(uJa + vIa, uJb + vIb); // h(j,i)
        }

        #pragma unroll
        for (int m = 0; m < 2; ++m)
            #pragma unroll
            for (int nf = 0; nf < 8; ++nf) {
                acc1[m][nf] = __builtin_amdgcn_mfma_f32_16x16x32_bf16(
                    a1f[m], bfr[nf], acc1[m][nf], 0, 0, 0);
                acc2[m][nf] = __builtin_amdgcn_mfma_f32_16x16x32_bf16(
                    a2f[m], bfr[nf], acc2[m][nf], 0, 0, 0);
            }
    }

    // ---- epilogue: bias + relu on both orders, sum, symmetric store
    int Ibase = I * 16, Jbase = J * 16;
    bool mirror = (I != J);
    #pragma unroll
    for (int m = 0; m < 2; ++m) {
        int i = Ibase + wave * 2 + m;
        #pragma unroll
        for (int nf = 0; nf < 8; ++nf) {
            int n = nf * 16 + llo;
            #pragma unroll
            for (int r = 0; r < 4; ++r) {
                int j = Jbase + lhi * 4 + r;   // C-frag row = (lane>>4)*4+reg
                float g1 = fmaxf(acc1[m][nf][r] + bias[nf], 0.f);
                float g2 = fmaxf(acc2[m][nf][r] + bias[nf], 0.f);
                float val = g1 + g2;
                out[((size_t)b * 4096 + i * 64 + j) * 128 + n] = val;
                if (mirror)
                    out[((size_t)b * 4096 + j * 64 + i) * 128 + n] = val;
            }
        }
    }
}

extern "C" void kernel_launch(void* const* d_in, const int* in_sizes, int n_in,
                              void* d_out, int out_size, void* d_ws, size_t ws_size,
                              hipStream_t stream)
{
    (void)in_sizes; (void)n_in; (void)out_size; (void)ws_size;
    const float* x  = (const float*)d_in[0];
    const float* W0 = (const float*)d_in[1];
    const float* b0 = (const float*)d_in[2];
    const float* W1 = (const float*)d_in[3];
    const float* b1 = (const float*)d_in[4];
    float* out = (float*)d_out;

    float* u = (float*)d_ws;                       // 32*64*128 fp32 = 1 MB
    float* v = u + (size_t)NB * NA * NC;           // 1 MB
    unsigned short* w1t = (unsigned short*)(v + (size_t)NB * NA * NC); // 32 KB

    prep_kernel<<<288, 128, 0, stream>>>(x, W0, b0, W1, u, v, w1t);
    pair_mlp_kernel<<<320, 512, 0, stream>>>(b1, u, v, w1t, out);
}

// Round 2
// 33.259 us; speedup vs baseline: 1.1841x; 1.1841x over previous
//
#include <hip/hip_runtime.h>
#include <hip/hip_bf16.h>

typedef float  f32x4  __attribute__((ext_vector_type(4)));
typedef __bf16 bf16x8 __attribute__((ext_vector_type(8)));
typedef unsigned int   u32x4 __attribute__((ext_vector_type(4)));
typedef unsigned short u16x4 __attribute__((ext_vector_type(4)));

#define NB 32
#define NA 64
#define NF 128
#define NC 128

// ---------------------------------------------------------------------------
// prep: u[b,a,c] = x[b,a,:] @ W0[0:128, c]
//       v[b,a,c] = x[b,a,:] @ W0[128:256, c] + b0[c]
//       w1t[n,k] = bf16(W1[k,n])
// blocks 0..255: u/v (8 atoms each). blocks 256..263: w1t transpose.
// ---------------------------------------------------------------------------
__global__ __launch_bounds__(512) void prep_kernel(
    const float* __restrict__ x, const float* __restrict__ W0,
    const float* __restrict__ b0, const float* __restrict__ W1,
    float* __restrict__ u, float* __restrict__ v,
    unsigned short* __restrict__ w1t)
{
    int blk = blockIdx.x;
    int tid = threadIdx.x;
    if (blk < 256) {
        __shared__ __align__(16) float xs[8 * 128];
        int b = blk >> 3;
        int g = blk & 7;
        if (tid < 256)
            ((f32x4*)xs)[tid] =
                ((const f32x4*)(x + (size_t)(b * NA + g * 8) * NF))[tid];
        __syncthreads();
        int c = tid & 127;
        int h = (tid >> 7) & 1;   // 0 -> u, 1 -> v
        int s = tid >> 8;         // atom sub-group: 4 atoms
        const float* wp = W0 + (size_t)h * 128 * NC + c;
        const float* xp = xs + s * 4 * 128;
        float a0 = 0.f, a1 = 0.f, a2 = 0.f, a3 = 0.f;
        #pragma unroll 8
        for (int f = 0; f < 128; ++f) {
            float w = wp[(size_t)f * NC];
            a0 = fmaf(xp[f],       w, a0);
            a1 = fmaf(xp[128 + f], w, a1);
            a2 = fmaf(xp[256 + f], w, a2);
            a3 = fmaf(xp[384 + f], w, a3);
        }
        int row = b * NA + g * 8 + s * 4;
        if (h == 0) {
            u[(size_t)(row + 0) * NC + c] = a0;
            u[(size_t)(row + 1) * NC + c] = a1;
            u[(size_t)(row + 2) * NC + c] = a2;
            u[(size_t)(row + 3) * NC + c] = a3;
        } else {
            float bb = b0[c];
            v[(size_t)(row + 0) * NC + c] = a0 + bb;
            v[(size_t)(row + 1) * NC + c] = a1 + bb;
            v[(size_t)(row + 2) * NC + c] = a2 + bb;
            v[(size_t)(row + 3) * NC + c] = a3 + bb;
        }
    } else {
        // w1t[n][k] = bf16(W1[k][n]); 4096 threads x 4 k-elements
        int t = (blk - 256) * 512 + tid;   // 0..4095
        int n = t >> 5;
        int k = (t & 31) * 4;
        u16x4 o;
        #pragma unroll
        for (int e = 0; e < 4; ++e) {
            float w = W1[(size_t)(k + e) * NC + n];
            o[e] = __builtin_bit_cast(unsigned short, (__bf16)w);
        }
        *(u16x4*)(w1t + (size_t)n * NC + k) = o;
    }
}

// ---------------------------------------------------------------------------
// main: block = (batch b, unordered 8x8 atom tile pair (I<=J)), 256 thr.
// pair-row r = i_local*8 + j_local in [0,64). Both orders:
//   D0[n][r] = sum_k W1[k][n] * relu(u_I[i]+v_J[j])[k]
//   D1[n][r] = sum_k W1[k][n] * relu(u_J[j]+v_I[i])[k]
//   out(i,j) = out(j,i) = relu(D0+b1) + relu(D1+b1)
// MFMA roles: A = W1^T frags (M=n), B = h frags (N=pair-rows) ->
// D reg-quad spans consecutive n -> vectorized dwordx4 stores.
// ---------------------------------------------------------------------------
__device__ inline bf16x8 relu_cvt_bf16(f32x4 a, f32x4 b)
{
    bf16x8 r;
    #pragma unroll
    for (int e = 0; e < 4; ++e) {
        r[e]     = (__bf16)fmaxf(a[e], 0.f);
        r[e + 4] = (__bf16)fmaxf(b[e], 0.f);
    }
    return r;
}

__global__ __launch_bounds__(256, 3) void pair_mlp_kernel(
    const float* __restrict__ b1g, const float* __restrict__ u,
    const float* __restrict__ v, const unsigned short* __restrict__ w1t,
    float* __restrict__ out)
{
    // 48 KB LDS -> 3 blocks/CU
    __shared__ __align__(16) float          u_s[16 * 128]; // rows 0-7: I, 8-15: J
    __shared__ __align__(16) float          v_s[16 * 128];
    __shared__ __align__(16) unsigned short w_s[128 * 128]; // W1^T [n][k] swizzled

    int blk = blockIdx.x;
    int b = blk / 36;
    int t = blk % 36;
    int I = 0;
    while (t >= 8 - I) { t -= 8 - I; ++I; }
    int J = I + t;

    int tid = threadIdx.x;

    // ---- stage u/v tiles (16B-chunk XOR swizzle on low 3 chunk bits)
    #pragma unroll
    for (int p = 0; p < 4; ++p) {
        int idx = p * 256 + tid;          // 0..1023
        int arr = idx >> 9;               // 0: u, 1: v
        int rem = idx & 511;
        int row = rem >> 5;               // 0..15
        int c   = rem & 31;               // 16B chunk in 512B row
        int ga  = b * NA + ((row < 8) ? (I * 8 + row) : (J * 8 + (row & 7)));
        const float* src = (arr ? v : u) + (size_t)ga * NC;
        float*       dst = (arr ? v_s : u_s) + row * 128;
        int sc = (c & 24) | ((c ^ row) & 7);
        ((f32x4*)dst)[sc] = ((const f32x4*)src)[c];
    }
    // ---- stage W1^T (bf16), XOR swizzle on low 3 chunk bits
    #pragma unroll
    for (int p = 0; p < 8; ++p) {
        int idx = p * 256 + tid;          // 0..2047
        int n = idx >> 4;
        int c = idx & 15;                 // 16B chunk in 256B row
        int sc = c ^ (n & 7);
        ((u32x4*)(w_s + n * 128))[sc] = ((const u32x4*)(w1t + (size_t)n * NC))[c];
    }
    __syncthreads();

    int wave = tid >> 6;
    int lane = tid & 63;
    int llo  = lane & 15;
    int lhi  = lane >> 4;
    int r    = wave * 16 + llo;   // pair-row this lane's B-frag/D-col covers
    int il   = r >> 3;            // i_local
    int jl   = r & 7;             // j_local

    f32x4 acc0[8], acc1[8];
    f32x4 z = {0.f, 0.f, 0.f, 0.f};
    #pragma unroll
    for (int nf = 0; nf < 8; ++nf) { acc0[nf] = z; acc1[nf] = z; }

    const float* uI = u_s + il * 128;
    const float* vI = v_s + il * 128;
    const float* uJ = u_s + (8 + jl) * 128;
    const float* vJ = v_s + (8 + jl) * 128;

    #pragma unroll
    for (int kk = 0; kk < 4; ++kk) {
        int kc  = kk * 8 + lhi * 2;   // f32 16B-chunk of this lane's k-slice
        int kc1 = kc + 1;
        int sA0 = (kc  & 24) | ((kc  ^ il) & 7);
        int sA1 = (kc1 & 24) | ((kc1 ^ il) & 7);
        int sB0 = (kc  & 24) | ((kc  ^ jl) & 7);
        int sB1 = (kc1 & 24) | ((kc1 ^ jl) & 7);

        f32x4 uIa = ((const f32x4*)uI)[sA0];
        f32x4 uIb = ((const f32x4*)uI)[sA1];
        f32x4 vIa = ((const f32x4*)vI)[sA0];
        f32x4 vIb = ((const f32x4*)vI)[sA1];
        f32x4 uJa = ((const f32x4*)uJ)[sB0];
        f32x4 uJb = ((const f32x4*)uJ)[sB1];
        f32x4 vJa = ((const f32x4*)vJ)[sB0];
        f32x4 vJb = ((const f32x4*)vJ)[sB1];

        bf16x8 h0 = relu_cvt_bf16(uIa + vJa, uIb + vJb);  // h(i,j)
        bf16x8 h1 = relu_cvt_bf16(uJa + vIa, uJb + vIb);  // h(j,i)

        int kcw = kk * 4 + lhi;       // bf16 16B-chunk of k-slice
        int scW = kcw ^ (llo & 7);
        #pragma unroll
        for (int nf = 0; nf < 8; ++nf) {
            bf16x8 wf = ((const bf16x8*)(w_s + (nf * 16 + llo) * 128))[scW];
            acc0[nf] = __builtin_amdgcn_mfma_f32_16x16x32_bf16(wf, h0, acc0[nf], 0, 0, 0);
            acc1[nf] = __builtin_amdgcn_mfma_f32_16x16x32_bf16(wf, h1, acc1[nf], 0, 0, 0);
        }
    }

    // ---- epilogue: n = nf*16 + lhi*4 + e  (consecutive e -> dwordx4 stores)
    int Ig = I * 8 + il;
    int Jg = J * 8 + jl;
    float* p1 = out + ((size_t)b * 4096 + Ig * 64 + Jg) * 128 + lhi * 4;
    float* p2 = out + ((size_t)b * 4096 + Jg * 64 + Ig) * 128 + lhi * 4;
    bool mirror = (I != J);
    #pragma unroll
    for (int nf = 0; nf < 8; ++nf) {
        f32x4 bias = *(const f32x4*)(b1g + nf * 16 + lhi * 4);
        f32x4 val;
        #pragma unroll
        for (int e = 0; e < 4; ++e)
            val[e] = fmaxf(acc0[nf][e] + bias[e], 0.f) +
                     fmaxf(acc1[nf][e] + bias[e], 0.f);
        __builtin_nontemporal_store(val, (f32x4*)(p1 + nf * 16));
        if (mirror)
            __builtin_nontemporal_store(val, (f32x4*)(p2 + nf * 16));
    }
}

extern "C" void kernel_launch(void* const* d_in, const int* in_sizes, int n_in,
                              void* d_out, int out_size, void* d_ws, size_t ws_size,
                              hipStream_t stream)
{
    (void)in_sizes; (void)n_in; (void)out_size; (void)ws_size;
    const float* x  = (const float*)d_in[0];
    const float* W0 = (const float*)d_in[1];
    const float* b0 = (const float*)d_in[2];
    const float* W1 = (const float*)d_in[3];
    const float* b1 = (const float*)d_in[4];
    float* out = (float*)d_out;

    float* u = (float*)d_ws;                                 // 1 MB
    float* v = u + (size_t)NB * NA * NC;                     // 1 MB
    unsigned short* w1t = (unsigned short*)(v + (size_t)NB * NA * NC); // 32 KB

    prep_kernel<<<264, 512, 0, stream>>>(x, W0, b0, W1, u, v, w1t);
    pair_mlp_kernel<<<32 * 36, 256, 0, stream>>>(b1, u, v, w1t, out);
}

// Round 3
// 31.559 us; speedup vs baseline: 1.2480x; 1.0539x over previous
//
#include <hip/hip_runtime.h>
#include <hip/hip_bf16.h>

typedef float  f32x4  __attribute__((ext_vector_type(4)));
typedef __bf16 bf16x8 __attribute__((ext_vector_type(8)));
typedef unsigned int   u32x4 __attribute__((ext_vector_type(4)));
typedef unsigned short u16x4 __attribute__((ext_vector_type(4)));

#define NB 32
#define NA 64
#define NF 128
#define NC 128

// ---------------------------------------------------------------------------
// prep: u[b,a,c] = x[b,a,:] @ W0[0:128, c]
//       v[b,a,c] = x[b,a,:] @ W0[128:256, c] + b0[c]
//       w1t[n,k] = bf16(W1[k,n])
// blocks 0..255: u/v (8 atoms each). blocks 256..263: w1t transpose.
// ---------------------------------------------------------------------------
__global__ __launch_bounds__(512) void prep_kernel(
    const float* __restrict__ x, const float* __restrict__ W0,
    const float* __restrict__ b0, const float* __restrict__ W1,
    float* __restrict__ u, float* __restrict__ v,
    unsigned short* __restrict__ w1t)
{
    int blk = blockIdx.x;
    int tid = threadIdx.x;
    if (blk < 256) {
        __shared__ __align__(16) float xs[8 * 128];
        int b = blk >> 3;
        int g = blk & 7;
        if (tid < 256)
            ((f32x4*)xs)[tid] =
                ((const f32x4*)(x + (size_t)(b * NA + g * 8) * NF))[tid];
        __syncthreads();
        int c = tid & 127;
        int h = (tid >> 7) & 1;   // 0 -> u, 1 -> v
        int s = tid >> 8;         // atom sub-group: 4 atoms
        const float* wp = W0 + (size_t)h * 128 * NC + c;
        const float* xp = xs + s * 4 * 128;
        float a0 = 0.f, a1 = 0.f, a2 = 0.f, a3 = 0.f;
        #pragma unroll 8
        for (int f = 0; f < 128; ++f) {
            float w = wp[(size_t)f * NC];
            a0 = fmaf(xp[f],       w, a0);
            a1 = fmaf(xp[128 + f], w, a1);
            a2 = fmaf(xp[256 + f], w, a2);
            a3 = fmaf(xp[384 + f], w, a3);
        }
        int row = b * NA + g * 8 + s * 4;
        if (h == 0) {
            u[(size_t)(row + 0) * NC + c] = a0;
            u[(size_t)(row + 1) * NC + c] = a1;
            u[(size_t)(row + 2) * NC + c] = a2;
            u[(size_t)(row + 3) * NC + c] = a3;
        } else {
            float bb = b0[c];
            v[(size_t)(row + 0) * NC + c] = a0 + bb;
            v[(size_t)(row + 1) * NC + c] = a1 + bb;
            v[(size_t)(row + 2) * NC + c] = a2 + bb;
            v[(size_t)(row + 3) * NC + c] = a3 + bb;
        }
    } else {
        // w1t[n][k] = bf16(W1[k][n]); 4096 threads x 4 k-elements
        int t = (blk - 256) * 512 + tid;   // 0..4095
        int n = t >> 5;
        int k = (t & 31) * 4;
        u16x4 o;
        #pragma unroll
        for (int e = 0; e < 4; ++e) {
            float w = W1[(size_t)(k + e) * NC + n];
            o[e] = __builtin_bit_cast(unsigned short, (__bf16)w);
        }
        *(u16x4*)(w1t + (size_t)n * NC + k) = o;
    }
}

// ---------------------------------------------------------------------------
// main: block = (batch b, unordered 8x8 atom tile pair (I<=J)), 256 thr.
// pair-row r = i_local*8 + j_local in [0,64). Both orders:
//   D0[n][r] = sum_k W1[k][n] * relu(u_I[i]+v_J[j])[k]
//   D1[n][r] = sum_k W1[k][n] * relu(u_J[j]+v_I[i])[k]
//   out(i,j) = out(j,i) = relu(D0+b1) + relu(D1+b1)
// MFMA roles: A = W1^T frags (M=n), B = h frags (N=pair-rows) ->
// D reg-quad spans consecutive n -> vectorized dwordx4 stores.
// Stores are PLAIN (not nontemporal): the per-instruction pattern is 16
// scattered 64B segments; L2 write-combining assembles the dense tile
// coverage into full-line HBM write-backs (the nt flag defeated this).
// ---------------------------------------------------------------------------
__device__ inline bf16x8 relu_cvt_bf16(f32x4 a, f32x4 b)
{
    bf16x8 r;
    #pragma unroll
    for (int e = 0; e < 4; ++e) {
        r[e]     = (__bf16)fmaxf(a[e], 0.f);
        r[e + 4] = (__bf16)fmaxf(b[e], 0.f);
    }
    return r;
}

__global__ __launch_bounds__(256, 3) void pair_mlp_kernel(
    const float* __restrict__ b1g, const float* __restrict__ u,
    const float* __restrict__ v, const unsigned short* __restrict__ w1t,
    float* __restrict__ out)
{
    // 48 KB LDS -> 3 blocks/CU
    __shared__ __align__(16) float          u_s[16 * 128]; // rows 0-7: I, 8-15: J
    __shared__ __align__(16) float          v_s[16 * 128];
    __shared__ __align__(16) unsigned short w_s[128 * 128]; // W1^T [n][k] swizzled

    int blk = blockIdx.x;
    int b = blk / 36;
    int t = blk % 36;
    int I = 0;
    while (t >= 8 - I) { t -= 8 - I; ++I; }
    int J = I + t;

    int tid = threadIdx.x;

    // ---- stage u/v tiles (16B-chunk XOR swizzle on low 3 chunk bits)
    #pragma unroll
    for (int p = 0; p < 4; ++p) {
        int idx = p * 256 + tid;          // 0..1023
        int arr = idx >> 9;               // 0: u, 1: v
        int rem = idx & 511;
        int row = rem >> 5;               // 0..15
        int c   = rem & 31;               // 16B chunk in 512B row
        int ga  = b * NA + ((row < 8) ? (I * 8 + row) : (J * 8 + (row & 7)));
        const float* src = (arr ? v : u) + (size_t)ga * NC;
        float*       dst = (arr ? v_s : u_s) + row * 128;
        int sc = (c & 24) | ((c ^ row) & 7);
        ((f32x4*)dst)[sc] = ((const f32x4*)src)[c];
    }
    // ---- stage W1^T (bf16), XOR swizzle on low 3 chunk bits
    #pragma unroll
    for (int p = 0; p < 8; ++p) {
        int idx = p * 256 + tid;          // 0..2047
        int n = idx >> 4;
        int c = idx & 15;                 // 16B chunk in 256B row
        int sc = c ^ (n & 7);
        ((u32x4*)(w_s + n * 128))[sc] = ((const u32x4*)(w1t + (size_t)n * NC))[c];
    }
    __syncthreads();

    int wave = tid >> 6;
    int lane = tid & 63;
    int llo  = lane & 15;
    int lhi  = lane >> 4;
    int r    = wave * 16 + llo;   // pair-row this lane's B-frag/D-col covers
    int il   = r >> 3;            // i_local
    int jl   = r & 7;             // j_local

    f32x4 acc0[8], acc1[8];
    f32x4 z = {0.f, 0.f, 0.f, 0.f};
    #pragma unroll
    for (int nf = 0; nf < 8; ++nf) { acc0[nf] = z; acc1[nf] = z; }

    const float* uI = u_s + il * 128;
    const float* vI = v_s + il * 128;
    const float* uJ = u_s + (8 + jl) * 128;
    const float* vJ = v_s + (8 + jl) * 128;

    #pragma unroll
    for (int kk = 0; kk < 4; ++kk) {
        int kc  = kk * 8 + lhi * 2;   // f32 16B-chunk of this lane's k-slice
        int kc1 = kc + 1;
        int sA0 = (kc  & 24) | ((kc  ^ il) & 7);
        int sA1 = (kc1 & 24) | ((kc1 ^ il) & 7);
        int sB0 = (kc  & 24) | ((kc  ^ jl) & 7);
        int sB1 = (kc1 & 24) | ((kc1 ^ jl) & 7);

        f32x4 uIa = ((const f32x4*)uI)[sA0];
        f32x4 uIb = ((const f32x4*)uI)[sA1];
        f32x4 vIa = ((const f32x4*)vI)[sA0];
        f32x4 vIb = ((const f32x4*)vI)[sA1];
        f32x4 uJa = ((const f32x4*)uJ)[sB0];
        f32x4 uJb = ((const f32x4*)uJ)[sB1];
        f32x4 vJa = ((const f32x4*)vJ)[sB0];
        f32x4 vJb = ((const f32x4*)vJ)[sB1];

        bf16x8 h0 = relu_cvt_bf16(uIa + vJa, uIb + vJb);  // h(i,j)
        bf16x8 h1 = relu_cvt_bf16(uJa + vIa, uJb + vIb);  // h(j,i)

        int kcw = kk * 4 + lhi;       // bf16 16B-chunk of k-slice
        int scW = kcw ^ (llo & 7);
        #pragma unroll
        for (int nf = 0; nf < 8; ++nf) {
            bf16x8 wf = ((const bf16x8*)(w_s + (nf * 16 + llo) * 128))[scW];
            acc0[nf] = __builtin_amdgcn_mfma_f32_16x16x32_bf16(wf, h0, acc0[nf], 0, 0, 0);
            acc1[nf] = __builtin_amdgcn_mfma_f32_16x16x32_bf16(wf, h1, acc1[nf], 0, 0, 0);
        }
    }

    // ---- epilogue: n = nf*16 + lhi*4 + e  (consecutive e -> dwordx4 stores)
    int Ig = I * 8 + il;
    int Jg = J * 8 + jl;
    float* p1 = out + ((size_t)b * 4096 + Ig * 64 + Jg) * 128 + lhi * 4;
    float* p2 = out + ((size_t)b * 4096 + Jg * 64 + Ig) * 128 + lhi * 4;
    bool mirror = (I != J);
    #pragma unroll
    for (int nf = 0; nf < 8; ++nf) {
        f32x4 bias = *(const f32x4*)(b1g + nf * 16 + lhi * 4);
        f32x4 val;
        #pragma unroll
        for (int e = 0; e < 4; ++e)
            val[e] = fmaxf(acc0[nf][e] + bias[e], 0.f) +
                     fmaxf(acc1[nf][e] + bias[e], 0.f);
        *(f32x4*)(p1 + nf * 16) = val;
        if (mirror)
            *(f32x4*)(p2 + nf * 16) = val;
    }
}

extern "C" void kernel_launch(void* const* d_in, const int* in_sizes, int n_in,
                              void* d_out, int out_size, void* d_ws, size_t ws_size,
                              hipStream_t stream)
{
    (void)in_sizes; (void)n_in; (void)out_size; (void)ws_size;
    const float* x  = (const float*)d_in[0];
    const float* W0 = (const float*)d_in[1];
    const float* b0 = (const float*)d_in[2];
    const float* W1 = (const float*)d_in[3];
    const float* b1 = (const float*)d_in[4];
    float* out = (float*)d_out;

    float* u = (float*)d_ws;                                 // 1 MB
    float* v = u + (size_t)NB * NA * NC;                     // 1 MB
    unsigned short* w1t = (unsigned short*)(v + (size_t)NB * NA * NC); // 32 KB

    prep_kernel<<<264, 512, 0, stream>>>(x, W0, b0, W1, u, v, w1t);
    pair_mlp_kernel<<<32 * 36, 256, 0, stream>>>(b1, u, v, w1t, out);
}

// Round 4
// 31.040 us; speedup vs baseline: 1.2688x; 1.0167x over previous
//
#include <hip/hip_runtime.h>
#include <hip/hip_bf16.h>

typedef float  f32x4  __attribute__((ext_vector_type(4)));
typedef __bf16 bf16x8 __attribute__((ext_vector_type(8)));
typedef unsigned int   u32x4 __attribute__((ext_vector_type(4)));
typedef unsigned short u16x4 __attribute__((ext_vector_type(4)));

#define NB 32
#define NA 64
#define NF 128
#define NC 128

// ---------------------------------------------------------------------------
// prep: u[b,a,c] = x[b,a,:] @ W0[0:128, c]
//       v[b,a,c] = x[b,a,:] @ W0[128:256, c] + b0[c]
//       w1t[n,k] = bf16(W1[k,n])
// ---------------------------------------------------------------------------
__global__ __launch_bounds__(512) void prep_kernel(
    const float* __restrict__ x, const float* __restrict__ W0,
    const float* __restrict__ b0, const float* __restrict__ W1,
    float* __restrict__ u, float* __restrict__ v,
    unsigned short* __restrict__ w1t)
{
    int blk = blockIdx.x;
    int tid = threadIdx.x;
    if (blk < 256) {
        __shared__ __align__(16) float xs[8 * 128];
        int b = blk >> 3;
        int g = blk & 7;
        if (tid < 256)
            ((f32x4*)xs)[tid] =
                ((const f32x4*)(x + (size_t)(b * NA + g * 8) * NF))[tid];
        __syncthreads();
        int c = tid & 127;
        int h = (tid >> 7) & 1;   // 0 -> u, 1 -> v
        int s = tid >> 8;         // atom sub-group: 4 atoms
        const float* wp = W0 + (size_t)h * 128 * NC + c;
        const float* xp = xs + s * 4 * 128;
        float a0 = 0.f, a1 = 0.f, a2 = 0.f, a3 = 0.f;
        #pragma unroll 8
        for (int f = 0; f < 128; ++f) {
            float w = wp[(size_t)f * NC];
            a0 = fmaf(xp[f],       w, a0);
            a1 = fmaf(xp[128 + f], w, a1);
            a2 = fmaf(xp[256 + f], w, a2);
            a3 = fmaf(xp[384 + f], w, a3);
        }
        int row = b * NA + g * 8 + s * 4;
        if (h == 0) {
            u[(size_t)(row + 0) * NC + c] = a0;
            u[(size_t)(row + 1) * NC + c] = a1;
            u[(size_t)(row + 2) * NC + c] = a2;
            u[(size_t)(row + 3) * NC + c] = a3;
        } else {
            float bb = b0[c];
            v[(size_t)(row + 0) * NC + c] = a0 + bb;
            v[(size_t)(row + 1) * NC + c] = a1 + bb;
            v[(size_t)(row + 2) * NC + c] = a2 + bb;
            v[(size_t)(row + 3) * NC + c] = a3 + bb;
        }
    } else {
        int t = (blk - 256) * 512 + tid;   // 0..4095
        int n = t >> 5;
        int k = (t & 31) * 4;
        u16x4 o;
        #pragma unroll
        for (int e = 0; e < 4; ++e) {
            float w = W1[(size_t)(k + e) * NC + n];
            o[e] = __builtin_bit_cast(unsigned short, (__bf16)w);
        }
        *(u16x4*)(w1t + (size_t)n * NC + k) = o;
    }
}

// ---------------------------------------------------------------------------
// main: block = (batch b, unordered 8x8 atom tile pair (I<=J)), 256 thr.
// Epilogue now stages the combined fp32 tile in LDS (overlay on w_s) and
// stores with fully-contiguous 1KB wave-instructions (full 128B lines),
// matching the fill kernel's line-level write behavior.
// ---------------------------------------------------------------------------
__device__ inline bf16x8 relu_cvt_bf16(f32x4 a, f32x4 b)
{
    bf16x8 r;
    #pragma unroll
    for (int e = 0; e < 4; ++e) {
        r[e]     = (__bf16)fmaxf(a[e], 0.f);
        r[e + 4] = (__bf16)fmaxf(b[e], 0.f);
    }
    return r;
}

__global__ __launch_bounds__(256, 3) void pair_mlp_kernel(
    const float* __restrict__ b1g, const float* __restrict__ u,
    const float* __restrict__ v, const unsigned short* __restrict__ w1t,
    float* __restrict__ out)
{
    // 48 KB LDS -> 3 blocks/CU. o_s (32KB) overlays w_s (dead after MFMAs).
    __shared__ __align__(16) unsigned char smem[48 * 1024];
    float*          u_s = (float*)smem;                        // 8 KB
    float*          v_s = (float*)(smem + 8 * 1024);           // 8 KB
    unsigned short* w_s = (unsigned short*)(smem + 16 * 1024); // 32 KB
    float*          o_s = (float*)(smem + 16 * 1024);          // 32 KB overlay

    int blk = blockIdx.x;
    int b = blk / 36;
    int t = blk % 36;
    int I = 0;
    while (t >= 8 - I) { t -= 8 - I; ++I; }
    int J = I + t;

    int tid = threadIdx.x;

    // ---- stage u/v tiles (16B-chunk XOR swizzle on low 3 chunk bits)
    #pragma unroll
    for (int p = 0; p < 4; ++p) {
        int idx = p * 256 + tid;          // 0..1023
        int arr = idx >> 9;               // 0: u, 1: v
        int rem = idx & 511;
        int row = rem >> 5;               // 0..15
        int c   = rem & 31;               // 16B chunk in 512B row
        int ga  = b * NA + ((row < 8) ? (I * 8 + row) : (J * 8 + (row & 7)));
        const float* src = (arr ? v : u) + (size_t)ga * NC;
        float*       dst = (arr ? v_s : u_s) + row * 128;
        int sc = (c & 24) | ((c ^ row) & 7);
        ((f32x4*)dst)[sc] = ((const f32x4*)src)[c];
    }
    // ---- stage W1^T (bf16), XOR swizzle on low 3 chunk bits
    #pragma unroll
    for (int p = 0; p < 8; ++p) {
        int idx = p * 256 + tid;          // 0..2047
        int n = idx >> 4;
        int c = idx & 15;                 // 16B chunk in 256B row
        int sc = c ^ (n & 7);
        ((u32x4*)(w_s + n * 128))[sc] = ((const u32x4*)(w1t + (size_t)n * NC))[c];
    }
    __syncthreads();

    int wave = tid >> 6;
    int lane = tid & 63;
    int llo  = lane & 15;
    int lhi  = lane >> 4;
    int r    = wave * 16 + llo;   // pair-row this lane's B-frag/D-col covers
    int il   = r >> 3;            // i_local
    int jl   = r & 7;             // j_local

    f32x4 acc0[8], acc1[8];
    f32x4 z = {0.f, 0.f, 0.f, 0.f};
    #pragma unroll
    for (int nf = 0; nf < 8; ++nf) { acc0[nf] = z; acc1[nf] = z; }

    const float* uI = u_s + il * 128;
    const float* vI = v_s + il * 128;
    const float* uJ = u_s + (8 + jl) * 128;
    const float* vJ = v_s + (8 + jl) * 128;

    #pragma unroll
    for (int kk = 0; kk < 4; ++kk) {
        int kc  = kk * 8 + lhi * 2;   // f32 16B-chunk of this lane's k-slice
        int kc1 = kc + 1;
        int sA0 = (kc  & 24) | ((kc  ^ il) & 7);
        int sA1 = (kc1 & 24) | ((kc1 ^ il) & 7);
        int sB0 = (kc  & 24) | ((kc  ^ jl) & 7);
        int sB1 = (kc1 & 24) | ((kc1 ^ jl) & 7);

        f32x4 uIa = ((const f32x4*)uI)[sA0];
        f32x4 uIb = ((const f32x4*)uI)[sA1];
        f32x4 vIa = ((const f32x4*)vI)[sA0];
        f32x4 vIb = ((const f32x4*)vI)[sA1];
        f32x4 uJa = ((const f32x4*)uJ)[sB0];
        f32x4 uJb = ((const f32x4*)uJ)[sB1];
        f32x4 vJa = ((const f32x4*)vJ)[sB0];
        f32x4 vJb = ((const f32x4*)vJ)[sB1];

        bf16x8 h0 = relu_cvt_bf16(uIa + vJa, uIb + vJb);  // h(i,j)
        bf16x8 h1 = relu_cvt_bf16(uJa + vIa, uJb + vIb);  // h(j,i)

        int kcw = kk * 4 + lhi;       // bf16 16B-chunk of k-slice
        int scW = kcw ^ (llo & 7);
        #pragma unroll
        for (int nf = 0; nf < 8; ++nf) {
            bf16x8 wf = ((const bf16x8*)(w_s + (nf * 16 + llo) * 128))[scW];
            acc0[nf] = __builtin_amdgcn_mfma_f32_16x16x32_bf16(wf, h0, acc0[nf], 0, 0, 0);
            acc1[nf] = __builtin_amdgcn_mfma_f32_16x16x32_bf16(wf, h1, acc1[nf], 0, 0, 0);
        }
    }

    // ---- wait for all waves' last w_s reads before overlaying with o_s
    __syncthreads();

    // ---- bias + relu + combine -> o_s[r][n], XOR-swizzled 16B chunks
    #pragma unroll
    for (int nf = 0; nf < 8; ++nf) {
        f32x4 bias = *(const f32x4*)(b1g + nf * 16 + lhi * 4);
        f32x4 val;
        #pragma unroll
        for (int e = 0; e < 4; ++e)
            val[e] = fmaxf(acc0[nf][e] + bias[e], 0.f) +
                     fmaxf(acc1[nf][e] + bias[e], 0.f);
        int c  = nf * 4 + lhi;                    // 16B chunk 0..31
        int sc = (c & 24) | ((c ^ r) & 7);
        ((f32x4*)(o_s + r * 128))[sc] = val;
    }
    __syncthreads();

    // ---- contiguous stores: 8 primary + 8 mirror chunks of 4KB each.
    // chunk q-instruction: lane l covers bytes q*1024 + l*16 (1KB contig).
    int cidx = lane & 31;                 // 16B chunk within 512B row
    int half = lane >> 5;                 // 0/1: which row of the 1KB pair
    bool mirror = (I != J);
    #pragma unroll
    for (int p = 0; p < 2; ++p) {
        int ch = wave * 2 + p;            // chunk id 0..7
        // primary: out rows (I*8+ch)*64 + J*8 .. J*8+7 ; value row = ch*8+jl
        float* dstp = out + ((size_t)b * 4096 + (I * 8 + ch) * 64 + J * 8) * 128;
        #pragma unroll
        for (int q = 0; q < 4; ++q) {
            int jrow = q * 2 + half;
            int vr   = ch * 8 + jrow;
            int sc   = (cidx & 24) | ((cidx ^ vr) & 7);
            f32x4 val = ((const f32x4*)(o_s + vr * 128))[sc];
            *(f32x4*)(dstp + q * 256 + lane * 4) = val;
        }
        if (mirror) {
            // mirror: out rows (J*8+ch)*64 + I*8 .. I*8+7 ; value row = irow*8+ch
            float* dstm = out + ((size_t)b * 4096 + (J * 8 + ch) * 64 + I * 8) * 128;
            #pragma unroll
            for (int q = 0; q < 4; ++q) {
                int irow = q * 2 + half;
                int vr   = irow * 8 + ch;
                int sc   = (cidx & 24) | ((cidx ^ vr) & 7);
                f32x4 val = ((const f32x4*)(o_s + vr * 128))[sc];
                *(f32x4*)(dstm + q * 256 + lane * 4) = val;
            }
        }
    }
}

extern "C" void kernel_launch(void* const* d_in, const int* in_sizes, int n_in,
                              void* d_out, int out_size, void* d_ws, size_t ws_size,
                              hipStream_t stream)
{
    (void)in_sizes; (void)n_in; (void)out_size; (void)ws_size;
    const float* x  = (const float*)d_in[0];
    const float* W0 = (const float*)d_in[1];
    const float* b0 = (const float*)d_in[2];
    const float* W1 = (const float*)d_in[3];
    const float* b1 = (const float*)d_in[4];
    float* out = (float*)d_out;

    float* u = (float*)d_ws;                                 // 1 MB
    float* v = u + (size_t)NB * NA * NC;                     // 1 MB
    unsigned short* w1t = (unsigned short*)(v + (size_t)NB * NA * NC); // 32 KB

    prep_kernel<<<264, 512, 0, stream>>>(x, W0, b0, W1, u, v, w1t);
    pair_mlp_kernel<<<32 * 36, 256, 0, stream>>>(b1, u, v, w1t, out);
}